// Round 1
// baseline (1439.015 us; speedup 1.0000x reference)
//
#include <hip/hip_runtime.h>
#include <hip/hip_bf16.h>
#include <math.h>

#define NODES_MAX 50000
#define GRAPHS 128
#define SCAN_B 256

// ---------------- small utility kernels ----------------

__global__ void k_zero_int(int* p, int n) {
    int i = blockIdx.x * blockDim.x + threadIdx.x;
    if (i < n) p[i] = 0;
}

__global__ void k_count(const int* __restrict__ dst, int* __restrict__ cnt, int E) {
    int i = blockIdx.x * blockDim.x + threadIdx.x;
    if (i < E) atomicAdd(&cnt[dst[i]], 1);
}

__global__ void k_dinv(const int* __restrict__ cnt, float* __restrict__ dinv, int n) {
    int i = blockIdx.x * blockDim.x + threadIdx.x;
    if (i < n) dinv[i] = rsqrtf((float)cnt[i] + 1.0f);  // +1 self loop
}

// exclusive scan over counts (3-kernel hierarchical)
__global__ void k_scan1(const int* __restrict__ cnt, int* __restrict__ excl,
                        int* __restrict__ bsum, int n) {
    __shared__ int sh[SCAN_B];
    int t = threadIdx.x;
    int i = blockIdx.x * SCAN_B + t;
    int v = (i < n) ? cnt[i] : 0;
    sh[t] = v;
    __syncthreads();
    for (int off = 1; off < SCAN_B; off <<= 1) {
        int x = (t >= off) ? sh[t - off] : 0;
        __syncthreads();
        sh[t] += x;
        __syncthreads();
    }
    if (i < n) excl[i] = sh[t] - v;
    if (t == SCAN_B - 1) bsum[blockIdx.x] = sh[t];
}

__global__ void k_scan2(int* __restrict__ bsum, int nb) {
    __shared__ int sh[SCAN_B];
    int t = threadIdx.x;
    int v = (t < nb) ? bsum[t] : 0;
    sh[t] = v;
    __syncthreads();
    for (int off = 1; off < SCAN_B; off <<= 1) {
        int x = (t >= off) ? sh[t - off] : 0;
        __syncthreads();
        sh[t] += x;
        __syncthreads();
    }
    if (t < nb) bsum[t] = sh[t] - v;  // exclusive block offsets
}

__global__ void k_scan3(int* __restrict__ rowstart, const int* __restrict__ bsum,
                        int* __restrict__ cursor, int n, int E) {
    int i = blockIdx.x * SCAN_B + threadIdx.x;
    if (i < n) {
        rowstart[i] += bsum[blockIdx.x];
        cursor[i] = 0;
    }
    if (i == 0) rowstart[n] = E;
}

__global__ void k_scatter_csr(const int* __restrict__ src, const int* __restrict__ dst,
                              const float* __restrict__ dinv, const int* __restrict__ rowstart,
                              int* __restrict__ cursor, int* __restrict__ csr_src,
                              float* __restrict__ csr_w, int E) {
    int e = blockIdx.x * blockDim.x + threadIdx.x;
    if (e >= E) return;
    int s = src[e], d = dst[e];
    int pos = rowstart[d] + atomicAdd(&cursor[d], 1);
    csr_src[pos] = s;
    csr_w[pos] = dinv[s] * dinv[d];
}

// ---------------- aggregation: agg[i] = sum_j Âij * m[j], CSR gather ----------------

template <int F>
__global__ void k_agg(const float* __restrict__ m, float* __restrict__ agg,
                      const int* __restrict__ rowstart, const int* __restrict__ csr_src,
                      const float* __restrict__ csr_w, const float* __restrict__ dinv, int n) {
    constexpr int TPN = F / 4;                       // threads per node (float4 each)
    constexpr int NPB = (TPN >= 64) ? 1 : (64 / TPN);
    int node = blockIdx.x * NPB + (NPB > 1 ? (int)(threadIdx.x / TPN) : 0);
    int f4 = (NPB > 1) ? (int)(threadIdx.x % TPN) : (int)threadIdx.x;
    if (node >= n) return;

    float di = dinv[node];
    const float4* mrow = (const float4*)(m + (size_t)node * F);
    float4 v = mrow[f4];
    float w0 = di * di;  // self loop
    float ax = v.x * w0, ay = v.y * w0, az = v.z * w0, aw = v.w * w0;

    int b = rowstart[node], e = rowstart[node + 1];
    for (int j = b; j < e; ++j) {
        int s = csr_src[j];
        float w = csr_w[j];
        float4 u = ((const float4*)(m + (size_t)s * F))[f4];
        ax += u.x * w; ay += u.y * w; az += u.z * w; aw += u.w * w;
    }
    float4 out; out.x = ax; out.y = ay; out.z = az; out.w = aw;
    ((float4*)(agg + (size_t)node * F))[f4] = out;
}

// ---------------- fp32 tiled GEMM with bias: C[M,N] = A[M,K] @ B[K,N] + bias ----------------

__global__ __launch_bounds__(256) void k_gemm_bias(const float* __restrict__ A,
                                                   const float* __restrict__ B,
                                                   const float* __restrict__ bias,
                                                   float* __restrict__ C,
                                                   int M, int N, int K) {
    __shared__ float As[16][64];
    __shared__ float Bs[16][64];
    int tid = threadIdx.x;
    int tx = tid & 15, ty = tid >> 4;
    int row0 = blockIdx.x * 64, col0 = blockIdx.y * 64;

    int a_m = tid >> 2, a_k4 = (tid & 3) * 4;   // A: 64 rows x 16 k, one float4/thread
    int b_k = tid >> 4, b_n4 = (tid & 15) * 4;  // B: 16 k x 64 n, one float4/thread

    float acc[4][4] = {};

    for (int k0 = 0; k0 < K; k0 += 16) {
        float4 av;
        int ar = row0 + a_m;
        if (ar < M) av = *(const float4*)(A + (size_t)ar * K + k0 + a_k4);
        else { av.x = av.y = av.z = av.w = 0.f; }
        As[a_k4 + 0][a_m] = av.x;
        As[a_k4 + 1][a_m] = av.y;
        As[a_k4 + 2][a_m] = av.z;
        As[a_k4 + 3][a_m] = av.w;

        float4 bv = *(const float4*)(B + (size_t)(k0 + b_k) * N + col0 + b_n4);
        *(float4*)&Bs[b_k][b_n4] = bv;
        __syncthreads();

#pragma unroll
        for (int k = 0; k < 16; ++k) {
            float4 a4 = *(const float4*)&As[k][ty * 4];
            float4 b4 = *(const float4*)&Bs[k][tx * 4];
            acc[0][0] += a4.x * b4.x; acc[0][1] += a4.x * b4.y; acc[0][2] += a4.x * b4.z; acc[0][3] += a4.x * b4.w;
            acc[1][0] += a4.y * b4.x; acc[1][1] += a4.y * b4.y; acc[1][2] += a4.y * b4.z; acc[1][3] += a4.y * b4.w;
            acc[2][0] += a4.z * b4.x; acc[2][1] += a4.z * b4.y; acc[2][2] += a4.z * b4.z; acc[2][3] += a4.z * b4.w;
            acc[3][0] += a4.w * b4.x; acc[3][1] += a4.w * b4.y; acc[3][2] += a4.w * b4.z; acc[3][3] += a4.w * b4.w;
        }
        __syncthreads();
    }

#pragma unroll
    for (int i = 0; i < 4; ++i) {
        int r = row0 + ty * 4 + i;
        if (r >= M) break;
        float* crow = C + (size_t)r * N + col0 + tx * 4;
        const float* brow = bias + col0 + tx * 4;
#pragma unroll
        for (int j = 0; j < 4; ++j) crow[j] = acc[i][j] + brow[j];
    }
}

// ---------------- LayerNorm (+optional LeakyReLU), in place, one row/block ----------------

template <int F, bool LRELU>
__global__ void k_ln(float* __restrict__ z, const float* __restrict__ g,
                     const float* __restrict__ be, int n) {
    constexpr int V = F / 128;  // 2 (F=256) or 4 (F=512), 1 (F=128)
    int row = blockIdx.x;
    if (row >= n) return;
    int t = threadIdx.x;
    float* base = z + (size_t)row * F + t * V;

    float f[V];
    if (V == 4) {
        float4 v = *(const float4*)base;
        f[0] = v.x; f[1] = v.y; f[2] = v.z; f[3] = v.w;
    } else if (V == 2) {
        float2 v = *(const float2*)base;
        f[0] = v.x; f[1] = v.y;
    } else {
        f[0] = base[0];
    }

    float s = 0.f, q = 0.f;
#pragma unroll
    for (int v = 0; v < V; ++v) { s += f[v]; q += f[v] * f[v]; }

    for (int off = 32; off > 0; off >>= 1) {
        s += __shfl_down(s, off);
        q += __shfl_down(q, off);
    }
    __shared__ float sh_s[2], sh_q[2];
    int wid = t >> 6;
    if ((t & 63) == 0) { sh_s[wid] = s; sh_q[wid] = q; }
    __syncthreads();
    float S = sh_s[0] + sh_s[1];
    float Q = sh_q[0] + sh_q[1];
    float mu = S * (1.0f / F);
    float var = Q * (1.0f / F) - mu * mu;
    float r = rsqrtf(var + 1e-5f);

    float o[V];
#pragma unroll
    for (int v = 0; v < V; ++v) {
        float y = (f[v] - mu) * r * g[t * V + v] + be[t * V + v];
        if (LRELU) y = (y > 0.f) ? y : 0.01f * y;
        o[v] = y;
    }
    if (V == 4) {
        float4 w; w.x = o[0]; w.y = o[1]; w.z = o[2]; w.w = o[3];
        *(float4*)base = w;
    } else if (V == 2) {
        float2 w; w.x = o[0]; w.y = o[1];
        *(float2*)base = w;
    } else {
        base[0] = o[0];
    }
}

// ---------------- per-graph mean pool (batch sorted) ----------------

__global__ void k_pool(const float* __restrict__ h, const int* __restrict__ batch,
                       float* __restrict__ pooled, int n) {
    int g = blockIdx.x;
    // lower_bound(batch, g) and lower_bound(batch, g+1)
    int lo = 0, hi = n;
    while (lo < hi) { int mid = (lo + hi) >> 1; if (batch[mid] < g) lo = mid + 1; else hi = mid; }
    int start = lo;
    lo = start; hi = n;
    while (lo < hi) { int mid = (lo + hi) >> 1; if (batch[mid] < g + 1) lo = mid + 1; else hi = mid; }
    int end = lo;
    float inv = 1.0f / fmaxf((float)(end - start), 1.0f);

    for (int f = threadIdx.x; f < 512; f += blockDim.x) {
        float s = 0.f;
        for (int i = start; i < end; ++i) s += h[(size_t)i * 512 + f];
        pooled[(size_t)g * 512 + f] = s * inv;
    }
}

// ---------------- final linear: out[G,128] = pooled[G,512] @ Wf[512,128] + bf ----------------

__global__ void k_final(const float* __restrict__ pooled, const float* __restrict__ Wf,
                        const float* __restrict__ bf, float* __restrict__ out) {
    int gph = blockIdx.x;
    int o = threadIdx.x;  // 128
    __shared__ float p[512];
    for (int k = threadIdx.x; k < 512; k += 128) p[k] = pooled[(size_t)gph * 512 + k];
    __syncthreads();
    float acc = bf[o];
#pragma unroll 8
    for (int k = 0; k < 512; ++k) acc += p[k] * Wf[(size_t)k * 128 + o];
    out[(size_t)gph * 128 + o] = acc;
}

// ---------------- host ----------------

static inline size_t align_up(size_t x) { return (x + 255) & ~(size_t)255; }

extern "C" void kernel_launch(void* const* d_in, const int* in_sizes, int n_in,
                              void* d_out, int out_size, void* d_ws, size_t ws_size,
                              hipStream_t stream) {
    const float* x    = (const float*)d_in[0];
    const int*   ei   = (const int*)d_in[1];
    const int*   batch= (const int*)d_in[2];
    const float* W1 = (const float*)d_in[4],  *b1 = (const float*)d_in[5];
    const float* g1 = (const float*)d_in[6],  *be1= (const float*)d_in[7];
    const float* W2 = (const float*)d_in[8],  *b2 = (const float*)d_in[9];
    const float* g2 = (const float*)d_in[10], *be2= (const float*)d_in[11];
    const float* W3 = (const float*)d_in[12], *b3 = (const float*)d_in[13];
    const float* g3 = (const float*)d_in[14], *be3= (const float*)d_in[15];
    const float* Wf = (const float*)d_in[16], *bf = (const float*)d_in[17];
    float* out = (float*)d_out;

    const int N = in_sizes[0] / 128;   // 50000
    const int E = in_sizes[1] / 2;     // 800000
    const int* src = ei;
    const int* dst = ei + E;

    char* ws = (char*)d_ws;
    size_t off = 0;
    auto take = [&](size_t bytes) { char* p = ws + off; off += align_up(bytes); return p; };

    float* buf0     = (float*)take((size_t)N * 512 * 4);
    float* buf1     = (float*)take((size_t)N * 512 * 4);
    float* dinv     = (float*)take((size_t)N * 4);
    int*   rowstart = (int*)  take((size_t)(N + 1) * 4);
    int*   cnt      = (int*)  take((size_t)N * 4);
    int*   cursor   = (int*)  take((size_t)N * 4);
    int*   bsum     = (int*)  take((size_t)SCAN_B * 4);
    int*   csr_src  = (int*)  take((size_t)E * 4);
    float* csr_w    = (float*)take((size_t)E * 4);
    float* pooled   = (float*)take((size_t)GRAPHS * 512 * 4);

    const int nb = (N + SCAN_B - 1) / SCAN_B;

    // degree + dinv + CSR build
    k_zero_int<<<(N + 255) / 256, 256, 0, stream>>>(cnt, N);
    k_count<<<(E + 255) / 256, 256, 0, stream>>>(dst, cnt, E);
    k_dinv<<<(N + 255) / 256, 256, 0, stream>>>(cnt, dinv, N);
    k_scan1<<<nb, SCAN_B, 0, stream>>>(cnt, rowstart, bsum, N);
    k_scan2<<<1, SCAN_B, 0, stream>>>(bsum, nb);
    k_scan3<<<nb, SCAN_B, 0, stream>>>(rowstart, bsum, cursor, N, E);
    k_scatter_csr<<<(E + 255) / 256, 256, 0, stream>>>(src, dst, dinv, rowstart, cursor,
                                                       csr_src, csr_w, E);

    // Layer 1: agg(x)[N,128] -> @W1+b1 [N,256] -> LN+lrelu
    k_agg<128><<<(N + 1) / 2, 64, 0, stream>>>(x, buf0, rowstart, csr_src, csr_w, dinv, N);
    {
        dim3 grid((N + 63) / 64, 256 / 64);
        k_gemm_bias<<<grid, 256, 0, stream>>>(buf0, W1, b1, buf1, N, 256, 128);
    }
    k_ln<256, true><<<N, 128, 0, stream>>>(buf1, g1, be1, N);

    // Layer 2: agg(h1)[N,256] -> @W2+b2 [N,512] -> LN+lrelu
    k_agg<256><<<N, 64, 0, stream>>>(buf1, buf0, rowstart, csr_src, csr_w, dinv, N);
    {
        dim3 grid((N + 63) / 64, 512 / 64);
        k_gemm_bias<<<grid, 256, 0, stream>>>(buf0, W2, b2, buf1, N, 512, 256);
    }
    k_ln<512, true><<<N, 128, 0, stream>>>(buf1, g2, be2, N);

    // Layer 3: agg(h2)[N,512] -> @W3+b3 [N,512] -> LN
    k_agg<512><<<N, 128, 0, stream>>>(buf1, buf0, rowstart, csr_src, csr_w, dinv, N);
    {
        dim3 grid((N + 63) / 64, 512 / 64);
        k_gemm_bias<<<grid, 256, 0, stream>>>(buf0, W3, b3, buf1, N, 512, 512);
    }
    k_ln<512, false><<<N, 128, 0, stream>>>(buf1, g3, be3, N);

    // pool + final linear
    k_pool<<<GRAPHS, 256, 0, stream>>>(buf1, batch, pooled, N);
    k_final<<<GRAPHS, 128, 0, stream>>>(pooled, Wf, bf, out);
}

// Round 2
// 658.864 us; speedup vs baseline: 2.1841x; 2.1841x over previous
//
#include <hip/hip_runtime.h>
#include <hip/hip_bf16.h>
#include <math.h>

#define GRAPHS 128
#define SCAN_B 256
#define BM 128
#define BN 128
#define BK 64

typedef __attribute__((ext_vector_type(8))) short bfrag8;   // 8 bf16 (4 VGPRs)
typedef __attribute__((ext_vector_type(4))) float f32x4;

__device__ inline unsigned short f2b(float f) {
    unsigned int u = __float_as_uint(f);
    unsigned int r = (u + 0x7fffu + ((u >> 16) & 1u)) >> 16;  // RNE
    return (unsigned short)r;
}
__device__ inline float b2f(unsigned short u) {
    return __uint_as_float(((unsigned int)u) << 16);
}

__device__ inline void gload16(const void* g, void* l) {
    typedef unsigned int __attribute__((address_space(1))) gu32;
    typedef unsigned int __attribute__((address_space(3))) su32;
    __builtin_amdgcn_global_load_lds((const gu32*)g, (su32*)l, 16, 0, 0);
}

// ---------------- CSR build ----------------

__global__ void k_zero_int(int* p, int n) {
    int i = blockIdx.x * blockDim.x + threadIdx.x;
    if (i < n) p[i] = 0;
}

__global__ void k_count(const int* __restrict__ dst, int* __restrict__ cnt, int E) {
    int i = blockIdx.x * blockDim.x + threadIdx.x;
    if (i < E) atomicAdd(&cnt[dst[i]], 1);
}

__global__ void k_dinv(const int* __restrict__ cnt, float* __restrict__ dinv, int n) {
    int i = blockIdx.x * blockDim.x + threadIdx.x;
    if (i < n) dinv[i] = rsqrtf((float)cnt[i] + 1.0f);
}

__global__ void k_scan1(const int* __restrict__ cnt, int* __restrict__ excl,
                        int* __restrict__ bsum, int n) {
    __shared__ int sh[SCAN_B];
    int t = threadIdx.x;
    int i = blockIdx.x * SCAN_B + t;
    int v = (i < n) ? cnt[i] : 0;
    sh[t] = v;
    __syncthreads();
    for (int off = 1; off < SCAN_B; off <<= 1) {
        int x = (t >= off) ? sh[t - off] : 0;
        __syncthreads();
        sh[t] += x;
        __syncthreads();
    }
    if (i < n) excl[i] = sh[t] - v;
    if (t == SCAN_B - 1) bsum[blockIdx.x] = sh[t];
}

__global__ void k_scan2(int* __restrict__ bsum, int nb) {
    __shared__ int sh[SCAN_B];
    int t = threadIdx.x;
    int v = (t < nb) ? bsum[t] : 0;
    sh[t] = v;
    __syncthreads();
    for (int off = 1; off < SCAN_B; off <<= 1) {
        int x = (t >= off) ? sh[t - off] : 0;
        __syncthreads();
        sh[t] += x;
        __syncthreads();
    }
    if (t < nb) bsum[t] = sh[t] - v;
}

__global__ void k_scan3(int* __restrict__ rowstart, const int* __restrict__ bsum,
                        int* __restrict__ cursor, int n, int E) {
    int i = blockIdx.x * SCAN_B + threadIdx.x;
    if (i < n) {
        rowstart[i] += bsum[blockIdx.x];
        cursor[i] = 0;
    }
    if (i == 0) rowstart[n] = E;
}

__global__ void k_scatter_csr(const int* __restrict__ src, const int* __restrict__ dst,
                              const float* __restrict__ dinv, const int* __restrict__ rowstart,
                              int* __restrict__ cursor, int* __restrict__ csr_src,
                              float* __restrict__ csr_w, int E) {
    int e = blockIdx.x * blockDim.x + threadIdx.x;
    if (e >= E) return;
    int s = src[e], d = dst[e];
    int pos = rowstart[d] + atomicAdd(&cursor[d], 1);
    csr_src[pos] = s;
    csr_w[pos] = dinv[s] * dinv[d];
}

// ---------------- weight transpose + bf16 cast: WT[n][k] = bf16(W[k][n]) ----------------

__global__ void k_wt(const float* __restrict__ W, unsigned short* __restrict__ WT,
                     int K, int N) {
    int idx = blockIdx.x * 256 + threadIdx.x;
    if (idx >= K * N) return;
    int k = idx / N, n2 = idx - k * N;
    WT[(size_t)n2 * K + k] = f2b(W[idx]);
}

// ---------------- x -> bf16 (padded rows zeroed) ----------------

__global__ void k_x2b(const float* __restrict__ x, unsigned short* __restrict__ xb,
                      int n, int mpad) {
    int idx = blockIdx.x * 256 + threadIdx.x;   // one float4 / thread
    if (idx >= mpad * 32) return;               // 128/4 quads per row
    int row = idx >> 5;
    float4 v = {0.f, 0.f, 0.f, 0.f};
    if (row < n) v = ((const float4*)x)[idx];
    ushort4 o;
    o.x = f2b(v.x); o.y = f2b(v.y); o.z = f2b(v.z); o.w = f2b(v.w);
    ((ushort4*)xb)[idx] = o;
}

// ---------------- aggregation (bf16 rows, fp32 accumulate, bf16 out) ----------------

__device__ inline void acc8(float* a, uint4 u, float w) {
    a[0] += b2f(u.x & 0xffffu) * w; a[1] += b2f(u.x >> 16) * w;
    a[2] += b2f(u.y & 0xffffu) * w; a[3] += b2f(u.y >> 16) * w;
    a[4] += b2f(u.z & 0xffffu) * w; a[5] += b2f(u.z >> 16) * w;
    a[6] += b2f(u.w & 0xffffu) * w; a[7] += b2f(u.w >> 16) * w;
}

template <int F>
__global__ void k_aggb(const unsigned short* __restrict__ m, unsigned short* __restrict__ agg,
                       const int* __restrict__ rowstart, const int* __restrict__ csr_src,
                       const float* __restrict__ csr_w, const float* __restrict__ dinv,
                       int n, int mpad) {
    constexpr int TPN = F / 8;        // threads per node, 16B (8 bf16) each
    constexpr int NPB = 256 / TPN;
    int node = blockIdx.x * NPB + (int)(threadIdx.x / TPN);
    int fo = (int)(threadIdx.x % TPN) * 8;
    if (node >= mpad) return;
    uint4* dst = (uint4*)(agg + (size_t)node * F + fo);
    if (node >= n) { uint4 z = {0u, 0u, 0u, 0u}; *dst = z; return; }

    float di = dinv[node];
    float a[8] = {};
    uint4 v = *(const uint4*)(m + (size_t)node * F + fo);
    acc8(a, v, di * di);  // self loop

    int b = rowstart[node], e = rowstart[node + 1];
    for (int j = b; j < e; ++j) {
        int s = csr_src[j];
        float w = csr_w[j];
        uint4 u = *(const uint4*)(m + (size_t)s * F + fo);
        acc8(a, u, w);
    }
    uint4 o;
    o.x = (unsigned)f2b(a[0]) | ((unsigned)f2b(a[1]) << 16);
    o.y = (unsigned)f2b(a[2]) | ((unsigned)f2b(a[3]) << 16);
    o.z = (unsigned)f2b(a[4]) | ((unsigned)f2b(a[5]) << 16);
    o.w = (unsigned)f2b(a[6]) | ((unsigned)f2b(a[7]) << 16);
    *dst = o;
}

// ---------------- bf16 MFMA GEMM: C[Mpad,N] = A[Mpad,K] @ BT[N,K]^T + bias ----------------
// m97 structure: 128x128 tile, BK=64, 4 waves 2x2 (64x64 each), global_load_lds staging,
// XOR swizzle (byte ^= (row&7)<<4) applied on BOTH global source and ds_read (rule #21).

__global__ __launch_bounds__(256) void k_gemm_bf16(
    const unsigned short* __restrict__ A, const unsigned short* __restrict__ BT,
    const float* __restrict__ bias, float* __restrict__ C, int K, int N) {
    __shared__ __align__(16) char sA[BM * BK * 2];
    __shared__ __align__(16) char sB[BN * BK * 2];

    const int tid = threadIdx.x;
    const int lane = tid & 63;
    const int wave = tid >> 6;
    const int wr = wave >> 1, wc = wave & 1;
    const size_t row0 = (size_t)blockIdx.x * BM;
    const size_t col0 = (size_t)blockIdx.y * BN;

    // staging: 4 chunks of 16B per thread per tile (A and B)
    const unsigned short* srcA[4];
    const unsigned short* srcB[4];
    char* dstA[4];
    char* dstB[4];
#pragma unroll
    for (int c = 0; c < 4; ++c) {
        int idx = c * 256 + tid;
        int row = idx >> 3;                       // 8 x 16B chunks per 128B row
        int cbl = ((idx & 7) << 4) ^ ((row & 7) << 4);  // inverse-swizzled logical byte col
        srcA[c] = A + (row0 + row) * K + (cbl >> 1);
        srcB[c] = BT + (col0 + row) * K + (cbl >> 1);
        dstA[c] = sA + idx * 16;
        dstB[c] = sB + idx * 16;
    }

    // fragment read offsets (swizzled)
    const int fr = lane & 15;
    const int fg = lane >> 4;               // k-group 0..3
    const int fsw = (lane & 7) << 4;        // swizzle term (row&7 == lane&7 here)
    int offA[4][2], offB[4][2];
#pragma unroll
    for (int t = 0; t < 4; ++t)
#pragma unroll
        for (int kk = 0; kk < 2; ++kk) {
            offA[t][kk] = (wr * 64 + t * 16 + fr) * (BK * 2) + ((kk * 64 + fg * 16) ^ fsw);
            offB[t][kk] = (wc * 64 + t * 16 + fr) * (BK * 2) + ((kk * 64 + fg * 16) ^ fsw);
        }

    f32x4 acc[4][4] = {};

    for (int k0 = 0; k0 < K; k0 += BK) {
#pragma unroll
        for (int c = 0; c < 4; ++c) gload16(srcA[c] + k0, dstA[c]);
#pragma unroll
        for (int c = 0; c < 4; ++c) gload16(srcB[c] + k0, dstB[c]);
        __syncthreads();
#pragma unroll
        for (int kk = 0; kk < 2; ++kk) {
            bfrag8 av[4], bv[4];
#pragma unroll
            for (int t = 0; t < 4; ++t) av[t] = *(const bfrag8*)(sA + offA[t][kk]);
#pragma unroll
            for (int t = 0; t < 4; ++t) bv[t] = *(const bfrag8*)(sB + offB[t][kk]);
#pragma unroll
            for (int i = 0; i < 4; ++i)
#pragma unroll
                for (int j = 0; j < 4; ++j)
                    acc[i][j] = __builtin_amdgcn_mfma_f32_16x16x32_bf16(av[i], bv[j],
                                                                        acc[i][j], 0, 0, 0);
        }
        __syncthreads();
    }

    // epilogue: C/D layout col=lane&15, row=(lane>>4)*4+q  (m89-verified)
#pragma unroll
    for (int i = 0; i < 4; ++i) {
#pragma unroll
        for (int j = 0; j < 4; ++j) {
            size_t r = row0 + wr * 64 + i * 16 + fg * 4;
            size_t cc = col0 + wc * 64 + j * 16 + fr;
            float bb = bias[cc];
#pragma unroll
            for (int q = 0; q < 4; ++q)
                C[(r + q) * N + cc] = acc[i][j][q] + bb;
        }
    }
}

// ---------------- LayerNorm fp32-in -> bf16-out (+optional LeakyReLU) ----------------

template <int F, bool LRELU>
__global__ void k_lnb(const float* __restrict__ z, unsigned short* __restrict__ h,
                      const float* __restrict__ g, const float* __restrict__ be,
                      int n, int mpad) {
    constexpr int V = F / 128;  // 2 or 4
    int row = blockIdx.x;
    int t = threadIdx.x;
    unsigned short* hb = h + (size_t)row * F + t * V;
    if (row >= n) {
#pragma unroll
        for (int vv = 0; vv < V; ++vv) hb[vv] = 0;
        return;
    }
    const float* base = z + (size_t)row * F + t * V;

    float f[V];
    if constexpr (V == 4) {
        float4 v = *(const float4*)base;
        f[0] = v.x; f[1] = v.y; f[2] = v.z; f[3] = v.w;
    } else {
        float2 v = *(const float2*)base;
        f[0] = v.x; f[1] = v.y;
    }

    float s = 0.f, q = 0.f;
#pragma unroll
    for (int v = 0; v < V; ++v) { s += f[v]; q += f[v] * f[v]; }
    for (int off = 32; off > 0; off >>= 1) {
        s += __shfl_down(s, off);
        q += __shfl_down(q, off);
    }
    __shared__ float sh_s[2], sh_q[2];
    int wid = t >> 6;
    if ((t & 63) == 0) { sh_s[wid] = s; sh_q[wid] = q; }
    __syncthreads();
    float S = sh_s[0] + sh_s[1];
    float Q = sh_q[0] + sh_q[1];
    float mu = S * (1.0f / F);
    float var = Q * (1.0f / F) - mu * mu;
    float r = rsqrtf(var + 1e-5f);

    float o[V];
#pragma unroll
    for (int v = 0; v < V; ++v) {
        float y = (f[v] - mu) * r * g[t * V + v] + be[t * V + v];
        if (LRELU) y = (y > 0.f) ? y : 0.01f * y;
        o[v] = y;
    }
    if constexpr (V == 4) {
        uint2 p;
        p.x = (unsigned)f2b(o[0]) | ((unsigned)f2b(o[1]) << 16);
        p.y = (unsigned)f2b(o[2]) | ((unsigned)f2b(o[3]) << 16);
        *(uint2*)hb = p;
    } else {
        *(unsigned int*)hb = (unsigned)f2b(o[0]) | ((unsigned)f2b(o[1]) << 16);
    }
}

// ---------------- per-graph mean pool (bf16 in, fp32 out) ----------------

__global__ void k_poolb(const unsigned short* __restrict__ h, const int* __restrict__ batch,
                        float* __restrict__ pooled, int n) {
    int gph = blockIdx.x;
    int lo = 0, hi = n;
    while (lo < hi) { int mid = (lo + hi) >> 1; if (batch[mid] < gph) lo = mid + 1; else hi = mid; }
    int start = lo;
    lo = start; hi = n;
    while (lo < hi) { int mid = (lo + hi) >> 1; if (batch[mid] < gph + 1) lo = mid + 1; else hi = mid; }
    int end = lo;
    float inv = 1.0f / fmaxf((float)(end - start), 1.0f);

    int t = threadIdx.x;  // 256 threads x 2 features
    float s0 = 0.f, s1 = 0.f;
    for (int i = start; i < end; ++i) {
        unsigned int u = *(const unsigned int*)(h + (size_t)i * 512 + t * 2);
        s0 += b2f(u & 0xffffu);
        s1 += b2f(u >> 16);
    }
    pooled[(size_t)gph * 512 + t * 2] = s0 * inv;
    pooled[(size_t)gph * 512 + t * 2 + 1] = s1 * inv;
}

// ---------------- final linear: out[G,128] = pooled[G,512] @ Wf[512,128] + bf ----------------

__global__ void k_final(const float* __restrict__ pooled, const float* __restrict__ Wf,
                        const float* __restrict__ bf, float* __restrict__ out) {
    int gph = blockIdx.x;
    int o = threadIdx.x;  // 128
    __shared__ float p[512];
    for (int k = threadIdx.x; k < 512; k += 128) p[k] = pooled[(size_t)gph * 512 + k];
    __syncthreads();
    float acc = bf[o];
#pragma unroll 8
    for (int k = 0; k < 512; ++k) acc += p[k] * Wf[(size_t)k * 128 + o];
    out[(size_t)gph * 128 + o] = acc;
}

// ---------------- host ----------------

static inline size_t align_up(size_t x) { return (x + 255) & ~(size_t)255; }

extern "C" void kernel_launch(void* const* d_in, const int* in_sizes, int n_in,
                              void* d_out, int out_size, void* d_ws, size_t ws_size,
                              hipStream_t stream) {
    const float* x     = (const float*)d_in[0];
    const int*   ei    = (const int*)d_in[1];
    const int*   batch = (const int*)d_in[2];
    const float* W1 = (const float*)d_in[4],  *b1 = (const float*)d_in[5];
    const float* g1 = (const float*)d_in[6],  *be1= (const float*)d_in[7];
    const float* W2 = (const float*)d_in[8],  *b2 = (const float*)d_in[9];
    const float* g2 = (const float*)d_in[10], *be2= (const float*)d_in[11];
    const float* W3 = (const float*)d_in[12], *b3 = (const float*)d_in[13];
    const float* g3 = (const float*)d_in[14], *be3= (const float*)d_in[15];
    const float* Wf = (const float*)d_in[16], *bf = (const float*)d_in[17];
    float* out = (float*)d_out;

    const int N = in_sizes[0] / 128;   // 50000
    const int E = in_sizes[1] / 2;     // 800000
    const int Mpad = ((N + BM - 1) / BM) * BM;   // 50048
    const int* src = ei;
    const int* dst = ei + E;

    char* ws = (char*)d_ws;
    size_t off = 0;
    auto take = [&](size_t bytes) { char* p = ws + off; off += align_up(bytes); return p; };

    float*          gout    = (float*)take((size_t)Mpad * 512 * 4);   // GEMM fp32 out
    unsigned short* aggb    = (unsigned short*)take((size_t)Mpad * 512 * 2);
    unsigned short* hb      = (unsigned short*)take((size_t)Mpad * 512 * 2);
    unsigned short* wt1     = (unsigned short*)take((size_t)256 * 128 * 2);
    unsigned short* wt2     = (unsigned short*)take((size_t)512 * 256 * 2);
    unsigned short* wt3     = (unsigned short*)take((size_t)512 * 512 * 2);
    float*          dinv    = (float*)take((size_t)N * 4);
    int*            rowstart= (int*)  take((size_t)(N + 1) * 4);
    int*            cnt     = (int*)  take((size_t)N * 4);
    int*            cursor  = (int*)  take((size_t)N * 4);
    int*            bsum    = (int*)  take((size_t)SCAN_B * 4);
    int*            csr_src = (int*)  take((size_t)E * 4);
    float*          csr_w   = (float*)take((size_t)E * 4);
    float*          pooled  = (float*)take((size_t)GRAPHS * 512 * 4);
    unsigned short* xb      = (unsigned short*)gout;  // alias: xb dead before GEMM1 writes gout

    const int nb = (N + SCAN_B - 1) / SCAN_B;

    // CSR build
    k_zero_int<<<(N + 255) / 256, 256, 0, stream>>>(cnt, N);
    k_count<<<(E + 255) / 256, 256, 0, stream>>>(dst, cnt, E);
    k_dinv<<<(N + 255) / 256, 256, 0, stream>>>(cnt, dinv, N);
    k_scan1<<<nb, SCAN_B, 0, stream>>>(cnt, rowstart, bsum, N);
    k_scan2<<<1, SCAN_B, 0, stream>>>(bsum, nb);
    k_scan3<<<nb, SCAN_B, 0, stream>>>(rowstart, bsum, cursor, N, E);
    k_scatter_csr<<<(E + 255) / 256, 256, 0, stream>>>(src, dst, dinv, rowstart, cursor,
                                                       csr_src, csr_w, E);

    // weights -> bf16 transposed
    k_wt<<<(128 * 256 + 255) / 256, 256, 0, stream>>>(W1, wt1, 128, 256);
    k_wt<<<(256 * 512 + 255) / 256, 256, 0, stream>>>(W2, wt2, 256, 512);
    k_wt<<<(512 * 512 + 255) / 256, 256, 0, stream>>>(W3, wt3, 512, 512);

    // x -> bf16 (padded)
    k_x2b<<<(Mpad * 32 + 255) / 256, 256, 0, stream>>>(x, xb, N, Mpad);

    // Layer 1
    k_aggb<128><<<Mpad / 16, 256, 0, stream>>>(xb, aggb, rowstart, csr_src, csr_w, dinv, N, Mpad);
    { dim3 grid(Mpad / BM, 256 / BN);
      k_gemm_bf16<<<grid, 256, 0, stream>>>(aggb, wt1, b1, gout, 128, 256); }
    k_lnb<256, true><<<Mpad, 128, 0, stream>>>(gout, hb, g1, be1, N, Mpad);

    // Layer 2
    k_aggb<256><<<Mpad / 8, 256, 0, stream>>>(hb, aggb, rowstart, csr_src, csr_w, dinv, N, Mpad);
    { dim3 grid(Mpad / BM, 512 / BN);
      k_gemm_bf16<<<grid, 256, 0, stream>>>(aggb, wt2, b2, gout, 256, 512); }
    k_lnb<512, true><<<Mpad, 128, 0, stream>>>(gout, hb, g2, be2, N, Mpad);

    // Layer 3
    k_aggb<512><<<Mpad / 4, 256, 0, stream>>>(hb, aggb, rowstart, csr_src, csr_w, dinv, N, Mpad);
    { dim3 grid(Mpad / BM, 512 / BN);
      k_gemm_bf16<<<grid, 256, 0, stream>>>(aggb, wt3, b3, gout, 512, 512); }
    k_lnb<512, false><<<Mpad, 128, 0, stream>>>(gout, hb, g3, be3, N, Mpad);

    // pool + final
    k_poolb<<<GRAPHS, 256, 0, stream>>>(hb, batch, pooled, N);
    k_final<<<GRAPHS, 128, 0, stream>>>(pooled, Wf, bf, out);
}

// Round 3
// 560.790 us; speedup vs baseline: 2.5660x; 1.1749x over previous
//
#include <hip/hip_runtime.h>
#include <hip/hip_bf16.h>
#include <math.h>

#define GRAPHS 128
#define SCAN_B 256
#define BM 128
#define BN 128
#define BK 64
#define PCH 128   // nodes per pooling block

typedef __attribute__((ext_vector_type(8))) short bfrag8;   // 8 bf16 (4 VGPRs)
typedef __attribute__((ext_vector_type(4))) float f32x4;

__device__ inline unsigned short f2b(float f) {
    unsigned int u = __float_as_uint(f);
    unsigned int r = (u + 0x7fffu + ((u >> 16) & 1u)) >> 16;  // RNE
    return (unsigned short)r;
}
__device__ inline float b2f(unsigned short u) {
    return __uint_as_float(((unsigned int)u) << 16);
}

__device__ inline void gload16(const void* g, void* l) {
    typedef unsigned int __attribute__((address_space(1))) gu32;
    typedef unsigned int __attribute__((address_space(3))) su32;
    __builtin_amdgcn_global_load_lds((const gu32*)g, (su32*)l, 16, 0, 0);
}

// ---------------- CSR build ----------------

__global__ void k_zero_int(int* p, int n) {
    int i = blockIdx.x * blockDim.x + threadIdx.x;
    if (i < n) p[i] = 0;
}

__global__ void k_count(const int* __restrict__ dst, int* __restrict__ cnt, int E) {
    int i = blockIdx.x * blockDim.x + threadIdx.x;
    if (i < E) atomicAdd(&cnt[dst[i]], 1);
}

__global__ void k_dinv(const int* __restrict__ cnt, float* __restrict__ dinv, int n) {
    int i = blockIdx.x * blockDim.x + threadIdx.x;
    if (i < n) dinv[i] = rsqrtf((float)cnt[i] + 1.0f);
}

__global__ void k_scan1(const int* __restrict__ cnt, int* __restrict__ excl,
                        int* __restrict__ bsum, int n) {
    __shared__ int sh[SCAN_B];
    int t = threadIdx.x;
    int i = blockIdx.x * SCAN_B + t;
    int v = (i < n) ? cnt[i] : 0;
    sh[t] = v;
    __syncthreads();
    for (int off = 1; off < SCAN_B; off <<= 1) {
        int x = (t >= off) ? sh[t - off] : 0;
        __syncthreads();
        sh[t] += x;
        __syncthreads();
    }
    if (i < n) excl[i] = sh[t] - v;
    if (t == SCAN_B - 1) bsum[blockIdx.x] = sh[t];
}

__global__ void k_scan2(int* __restrict__ bsum, int nb) {
    __shared__ int sh[SCAN_B];
    int t = threadIdx.x;
    int v = (t < nb) ? bsum[t] : 0;
    sh[t] = v;
    __syncthreads();
    for (int off = 1; off < SCAN_B; off <<= 1) {
        int x = (t >= off) ? sh[t - off] : 0;
        __syncthreads();
        sh[t] += x;
        __syncthreads();
    }
    if (t < nb) bsum[t] = sh[t] - v;
}

__global__ void k_scan3(int* __restrict__ rowstart, const int* __restrict__ bsum,
                        int* __restrict__ cursor, int n, int E) {
    int i = blockIdx.x * SCAN_B + threadIdx.x;
    if (i < n) {
        rowstart[i] += bsum[blockIdx.x];
        cursor[i] = 0;
    }
    if (i == 0) rowstart[n] = E;
}

__global__ void k_scatter_csr(const int* __restrict__ src, const int* __restrict__ dst,
                              const float* __restrict__ dinv, const int* __restrict__ rowstart,
                              int* __restrict__ cursor, int2* __restrict__ csr, int E) {
    int e = blockIdx.x * blockDim.x + threadIdx.x;
    if (e >= E) return;
    int s = src[e], d = dst[e];
    int pos = rowstart[d] + atomicAdd(&cursor[d], 1);
    int2 c;
    c.x = s;
    c.y = __float_as_int(dinv[s] * dinv[d]);
    csr[pos] = c;
}

// ---------------- weight transpose + bf16 cast: WT[n][k] = bf16(W[k][n]) ----------------

__global__ void k_wt(const float* __restrict__ W, unsigned short* __restrict__ WT,
                     int K, int N) {
    int idx = blockIdx.x * 256 + threadIdx.x;
    if (idx >= K * N) return;
    int k = idx / N, n2 = idx - k * N;
    WT[(size_t)n2 * K + k] = f2b(W[idx]);
}

// ---------------- x -> bf16 (padded rows zeroed) ----------------

__global__ void k_x2b(const float* __restrict__ x, unsigned short* __restrict__ xb,
                      int n, int mpad) {
    int idx = blockIdx.x * 256 + threadIdx.x;   // one float4 / thread
    if (idx >= mpad * 32) return;               // 128/4 quads per row
    int row = idx >> 5;
    float4 v = {0.f, 0.f, 0.f, 0.f};
    if (row < n) v = ((const float4*)x)[idx];
    ushort4 o;
    o.x = f2b(v.x); o.y = f2b(v.y); o.z = f2b(v.z); o.w = f2b(v.w);
    ((ushort4*)xb)[idx] = o;
}

// ---------------- aggregation (bf16 rows, fp32 accumulate, bf16 out) ----------------

__device__ inline void acc8(float* a, uint4 u, float w) {
    a[0] += b2f(u.x & 0xffffu) * w; a[1] += b2f(u.x >> 16) * w;
    a[2] += b2f(u.y & 0xffffu) * w; a[3] += b2f(u.y >> 16) * w;
    a[4] += b2f(u.z & 0xffffu) * w; a[5] += b2f(u.z >> 16) * w;
    a[6] += b2f(u.w & 0xffffu) * w; a[7] += b2f(u.w >> 16) * w;
}

template <int F>
__global__ void k_aggb(const unsigned short* __restrict__ m, unsigned short* __restrict__ agg,
                       const int* __restrict__ rowstart, const int2* __restrict__ csr,
                       const float* __restrict__ dinv, int n, int mpad) {
    constexpr int TPN = F / 8;        // threads per node, 16B (8 bf16) each
    constexpr int NPB = 256 / TPN;
    int node = blockIdx.x * NPB + (int)(threadIdx.x / TPN);
    int fo = (int)(threadIdx.x % TPN) * 8;
    if (node >= mpad) return;
    uint4* dst = (uint4*)(agg + (size_t)node * F + fo);
    if (node >= n) { uint4 z = {0u, 0u, 0u, 0u}; *dst = z; return; }

    const unsigned short* mf = m + fo;
    float di = dinv[node];
    float a[8] = {};
    acc8(a, *(const uint4*)(mf + (size_t)node * F), di * di);  // self loop

    int b = rowstart[node], e = rowstart[node + 1];
    int j = b;
    // unroll-4: issue 4 independent row loads before the accumulate chain
    for (; j + 4 <= e; j += 4) {
        int2 c0 = csr[j], c1 = csr[j + 1], c2 = csr[j + 2], c3 = csr[j + 3];
        uint4 u0 = *(const uint4*)(mf + (size_t)c0.x * F);
        uint4 u1 = *(const uint4*)(mf + (size_t)c1.x * F);
        uint4 u2 = *(const uint4*)(mf + (size_t)c2.x * F);
        uint4 u3 = *(const uint4*)(mf + (size_t)c3.x * F);
        acc8(a, u0, __int_as_float(c0.y));
        acc8(a, u1, __int_as_float(c1.y));
        acc8(a, u2, __int_as_float(c2.y));
        acc8(a, u3, __int_as_float(c3.y));
    }
    for (; j < e; ++j) {
        int2 c = csr[j];
        uint4 u = *(const uint4*)(mf + (size_t)c.x * F);
        acc8(a, u, __int_as_float(c.y));
    }
    uint4 o;
    o.x = (unsigned)f2b(a[0]) | ((unsigned)f2b(a[1]) << 16);
    o.y = (unsigned)f2b(a[2]) | ((unsigned)f2b(a[3]) << 16);
    o.z = (unsigned)f2b(a[4]) | ((unsigned)f2b(a[5]) << 16);
    o.w = (unsigned)f2b(a[6]) | ((unsigned)f2b(a[7]) << 16);
    *dst = o;
}

// ---------------- bf16 MFMA GEMM: C[Mpad,N] = A[Mpad,K] @ BT[N,K]^T + bias ----------------

__global__ __launch_bounds__(256) void k_gemm_bf16(
    const unsigned short* __restrict__ A, const unsigned short* __restrict__ BT,
    const float* __restrict__ bias, float* __restrict__ C, int K, int N) {
    __shared__ __align__(16) char sA[BM * BK * 2];
    __shared__ __align__(16) char sB[BN * BK * 2];

    const int tid = threadIdx.x;
    const int lane = tid & 63;
    const int wave = tid >> 6;
    const int wr = wave >> 1, wc = wave & 1;
    const size_t row0 = (size_t)blockIdx.x * BM;
    const size_t col0 = (size_t)blockIdx.y * BN;

    const unsigned short* srcA[4];
    const unsigned short* srcB[4];
    char* dstA[4];
    char* dstB[4];
#pragma unroll
    for (int c = 0; c < 4; ++c) {
        int idx = c * 256 + tid;
        int row = idx >> 3;
        int cbl = ((idx & 7) << 4) ^ ((row & 7) << 4);
        srcA[c] = A + (row0 + row) * K + (cbl >> 1);
        srcB[c] = BT + (col0 + row) * K + (cbl >> 1);
        dstA[c] = sA + idx * 16;
        dstB[c] = sB + idx * 16;
    }

    const int fr = lane & 15;
    const int fg = lane >> 4;
    const int fsw = (lane & 7) << 4;
    int offA[4][2], offB[4][2];
#pragma unroll
    for (int t = 0; t < 4; ++t)
#pragma unroll
        for (int kk = 0; kk < 2; ++kk) {
            offA[t][kk] = (wr * 64 + t * 16 + fr) * (BK * 2) + ((kk * 64 + fg * 16) ^ fsw);
            offB[t][kk] = (wc * 64 + t * 16 + fr) * (BK * 2) + ((kk * 64 + fg * 16) ^ fsw);
        }

    f32x4 acc[4][4] = {};

    for (int k0 = 0; k0 < K; k0 += BK) {
#pragma unroll
        for (int c = 0; c < 4; ++c) gload16(srcA[c] + k0, dstA[c]);
#pragma unroll
        for (int c = 0; c < 4; ++c) gload16(srcB[c] + k0, dstB[c]);
        __syncthreads();
#pragma unroll
        for (int kk = 0; kk < 2; ++kk) {
            bfrag8 av[4], bv[4];
#pragma unroll
            for (int t = 0; t < 4; ++t) av[t] = *(const bfrag8*)(sA + offA[t][kk]);
#pragma unroll
            for (int t = 0; t < 4; ++t) bv[t] = *(const bfrag8*)(sB + offB[t][kk]);
#pragma unroll
            for (int i = 0; i < 4; ++i)
#pragma unroll
                for (int j = 0; j < 4; ++j)
                    acc[i][j] = __builtin_amdgcn_mfma_f32_16x16x32_bf16(av[i], bv[j],
                                                                        acc[i][j], 0, 0, 0);
        }
        __syncthreads();
    }

#pragma unroll
    for (int i = 0; i < 4; ++i) {
#pragma unroll
        for (int j = 0; j < 4; ++j) {
            size_t r = row0 + wr * 64 + i * 16 + fg * 4;
            size_t cc = col0 + wc * 64 + j * 16 + fr;
            float bb = bias[cc];
#pragma unroll
            for (int q = 0; q < 4; ++q)
                C[(r + q) * N + cc] = acc[i][j][q] + bb;
        }
    }
}

// ---------------- LayerNorm fp32-in -> bf16-out (+optional LeakyReLU) ----------------

template <int F, bool LRELU>
__global__ void k_lnb(const float* __restrict__ z, unsigned short* __restrict__ h,
                      const float* __restrict__ g, const float* __restrict__ be,
                      int n, int mpad) {
    constexpr int V = F / 128;
    int row = blockIdx.x;
    int t = threadIdx.x;
    unsigned short* hb = h + (size_t)row * F + t * V;
    if (row >= n) {
#pragma unroll
        for (int vv = 0; vv < V; ++vv) hb[vv] = 0;
        return;
    }
    const float* base = z + (size_t)row * F + t * V;

    float f[V];
    if constexpr (V == 4) {
        float4 v = *(const float4*)base;
        f[0] = v.x; f[1] = v.y; f[2] = v.z; f[3] = v.w;
    } else {
        float2 v = *(const float2*)base;
        f[0] = v.x; f[1] = v.y;
    }

    float s = 0.f, q = 0.f;
#pragma unroll
    for (int v = 0; v < V; ++v) { s += f[v]; q += f[v] * f[v]; }
    for (int off = 32; off > 0; off >>= 1) {
        s += __shfl_down(s, off);
        q += __shfl_down(q, off);
    }
    __shared__ float sh_s[2], sh_q[2];
    int wid = t >> 6;
    if ((t & 63) == 0) { sh_s[wid] = s; sh_q[wid] = q; }
    __syncthreads();
    float S = sh_s[0] + sh_s[1];
    float Q = sh_q[0] + sh_q[1];
    float mu = S * (1.0f / F);
    float var = Q * (1.0f / F) - mu * mu;
    float r = rsqrtf(var + 1e-5f);

    float o[V];
#pragma unroll
    for (int v = 0; v < V; ++v) {
        float y = (f[v] - mu) * r * g[t * V + v] + be[t * V + v];
        if (LRELU) y = (y > 0.f) ? y : 0.01f * y;
        o[v] = y;
    }
    if constexpr (V == 4) {
        uint2 p;
        p.x = (unsigned)f2b(o[0]) | ((unsigned)f2b(o[1]) << 16);
        p.y = (unsigned)f2b(o[2]) | ((unsigned)f2b(o[3]) << 16);
        *(uint2*)hb = p;
    } else {
        *(unsigned int*)hb = (unsigned)f2b(o[0]) | ((unsigned)f2b(o[1]) << 16);
    }
}

// ---------------- pooling: chunked partial sums + atomics ----------------

__global__ void k_pzero(float* p) { p[blockIdx.x * 256 + threadIdx.x] = 0.f; }

__global__ void k_pool2(const unsigned short* __restrict__ h, const int* __restrict__ batch,
                        float* __restrict__ pooled, int n) {
    int i0 = blockIdx.x * PCH;
    int iend = i0 + PCH; if (iend > n) iend = n;
    int t = threadIdx.x;  // 256 threads x 2 features
    float s0 = 0.f, s1 = 0.f;
    int cur = batch[i0];
    for (int i = i0; i < iend; ++i) {
        int g = batch[i];
        if (g != cur) {  // block-uniform branch (same i for all threads)
            atomicAdd(&pooled[(size_t)cur * 512 + t * 2], s0);
            atomicAdd(&pooled[(size_t)cur * 512 + t * 2 + 1], s1);
            s0 = s1 = 0.f;
            cur = g;
        }
        unsigned int u = *(const unsigned int*)(h + (size_t)i * 512 + t * 2);
        s0 += b2f(u & 0xffffu);
        s1 += b2f(u >> 16);
    }
    atomicAdd(&pooled[(size_t)cur * 512 + t * 2], s0);
    atomicAdd(&pooled[(size_t)cur * 512 + t * 2 + 1], s1);
}

// ---------------- final linear: out[G,128] = (pooled/cnt) @ Wf + bf ----------------

__global__ void k_final(const float* __restrict__ pooled, const int* __restrict__ batch,
                        const float* __restrict__ Wf, const float* __restrict__ bf,
                        float* __restrict__ out, int n) {
    int gph = blockIdx.x;
    int o = threadIdx.x;  // 128
    int lo = 0, hi = n;
    while (lo < hi) { int mid = (lo + hi) >> 1; if (batch[mid] < gph) lo = mid + 1; else hi = mid; }
    int start = lo;
    lo = start; hi = n;
    while (lo < hi) { int mid = (lo + hi) >> 1; if (batch[mid] < gph + 1) lo = mid + 1; else hi = mid; }
    int end = lo;
    float inv = 1.0f / fmaxf((float)(end - start), 1.0f);

    __shared__ float p[512];
    for (int k = threadIdx.x; k < 512; k += 128) p[k] = pooled[(size_t)gph * 512 + k] * inv;
    __syncthreads();
    float acc = bf[o];
#pragma unroll 8
    for (int k = 0; k < 512; ++k) acc += p[k] * Wf[(size_t)k * 128 + o];
    out[(size_t)gph * 128 + o] = acc;
}

// ---------------- host ----------------

static inline size_t align_up(size_t x) { return (x + 255) & ~(size_t)255; }

extern "C" void kernel_launch(void* const* d_in, const int* in_sizes, int n_in,
                              void* d_out, int out_size, void* d_ws, size_t ws_size,
                              hipStream_t stream) {
    const float* x     = (const float*)d_in[0];
    const int*   ei    = (const int*)d_in[1];
    const int*   batch = (const int*)d_in[2];
    const float* W1 = (const float*)d_in[4],  *b1 = (const float*)d_in[5];
    const float* g1 = (const float*)d_in[6],  *be1= (const float*)d_in[7];
    const float* W2 = (const float*)d_in[8],  *b2 = (const float*)d_in[9];
    const float* g2 = (const float*)d_in[10], *be2= (const float*)d_in[11];
    const float* W3 = (const float*)d_in[12], *b3 = (const float*)d_in[13];
    const float* g3 = (const float*)d_in[14], *be3= (const float*)d_in[15];
    const float* Wf = (const float*)d_in[16], *bf = (const float*)d_in[17];
    float* out = (float*)d_out;

    const int N = in_sizes[0] / 128;   // 50000
    const int E = in_sizes[1] / 2;     // 800000
    const int Mpad = ((N + BM - 1) / BM) * BM;   // 50048
    const int* src = ei;
    const int* dst = ei + E;

    char* ws = (char*)d_ws;
    size_t off = 0;
    auto take = [&](size_t bytes) { char* p = ws + off; off += align_up(bytes); return p; };

    float*          gout    = (float*)take((size_t)Mpad * 512 * 4);
    unsigned short* aggb    = (unsigned short*)take((size_t)Mpad * 512 * 2);
    unsigned short* hb      = (unsigned short*)take((size_t)Mpad * 512 * 2);
    unsigned short* wt1     = (unsigned short*)take((size_t)256 * 128 * 2);
    unsigned short* wt2     = (unsigned short*)take((size_t)512 * 256 * 2);
    unsigned short* wt3     = (unsigned short*)take((size_t)512 * 512 * 2);
    float*          dinv    = (float*)take((size_t)N * 4);
    int*            rowstart= (int*)  take((size_t)(N + 1) * 4);
    int*            cnt     = (int*)  take((size_t)N * 4);
    int*            cursor  = (int*)  take((size_t)N * 4);
    int*            bsum    = (int*)  take((size_t)SCAN_B * 4);
    int2*           csr     = (int2*) take((size_t)E * 8);
    float*          pooled  = (float*)take((size_t)GRAPHS * 512 * 4);
    unsigned short* xb      = (unsigned short*)gout;  // alias: xb dead before GEMM1 writes gout

    const int nb = (N + SCAN_B - 1) / SCAN_B;

    // CSR build
    k_zero_int<<<(N + 255) / 256, 256, 0, stream>>>(cnt, N);
    k_count<<<(E + 255) / 256, 256, 0, stream>>>(dst, cnt, E);
    k_dinv<<<(N + 255) / 256, 256, 0, stream>>>(cnt, dinv, N);
    k_scan1<<<nb, SCAN_B, 0, stream>>>(cnt, rowstart, bsum, N);
    k_scan2<<<1, SCAN_B, 0, stream>>>(bsum, nb);
    k_scan3<<<nb, SCAN_B, 0, stream>>>(rowstart, bsum, cursor, N, E);
    k_scatter_csr<<<(E + 255) / 256, 256, 0, stream>>>(src, dst, dinv, rowstart, cursor, csr, E);

    // weights -> bf16 transposed
    k_wt<<<(128 * 256 + 255) / 256, 256, 0, stream>>>(W1, wt1, 128, 256);
    k_wt<<<(256 * 512 + 255) / 256, 256, 0, stream>>>(W2, wt2, 256, 512);
    k_wt<<<(512 * 512 + 255) / 256, 256, 0, stream>>>(W3, wt3, 512, 512);

    // x -> bf16 (padded)
    k_x2b<<<(Mpad * 32 + 255) / 256, 256, 0, stream>>>(x, xb, N, Mpad);

    // Layer 1
    k_aggb<128><<<Mpad / 16, 256, 0, stream>>>(xb, aggb, rowstart, csr, dinv, N, Mpad);
    { dim3 grid(Mpad / BM, 256 / BN);
      k_gemm_bf16<<<grid, 256, 0, stream>>>(aggb, wt1, b1, gout, 128, 256); }
    k_lnb<256, true><<<Mpad, 128, 0, stream>>>(gout, hb, g1, be1, N, Mpad);

    // Layer 2
    k_aggb<256><<<Mpad / 8, 256, 0, stream>>>(hb, aggb, rowstart, csr, dinv, N, Mpad);
    { dim3 grid(Mpad / BM, 512 / BN);
      k_gemm_bf16<<<grid, 256, 0, stream>>>(aggb, wt2, b2, gout, 256, 512); }
    k_lnb<512, true><<<Mpad, 128, 0, stream>>>(gout, hb, g2, be2, N, Mpad);

    // Layer 3
    k_aggb<512><<<Mpad / 4, 256, 0, stream>>>(hb, aggb, rowstart, csr, dinv, N, Mpad);
    { dim3 grid(Mpad / BM, 512 / BN);
      k_gemm_bf16<<<grid, 256, 0, stream>>>(aggb, wt3, b3, gout, 512, 512); }
    k_lnb<512, false><<<Mpad, 128, 0, stream>>>(gout, hb, g3, be3, N, Mpad);

    // pool + final
    k_pzero<<<GRAPHS * 512 / 256, 256, 0, stream>>>(pooled);
    k_pool2<<<(N + PCH - 1) / PCH, 256, 0, stream>>>(hb, batch, pooled, N);
    k_final<<<GRAPHS, 128, 0, stream>>>(pooled, batch, Wf, bf, out, N);
}

// Round 4
// 548.811 us; speedup vs baseline: 2.6221x; 1.0218x over previous
//
#include <hip/hip_runtime.h>
#include <hip/hip_bf16.h>
#include <math.h>

#define GRAPHS 128
#define SCAN_B 256
#define BK 64
#define PCH 128   // nodes per pooling block

typedef __attribute__((ext_vector_type(8))) short bfrag8;   // 8 bf16 (4 VGPRs)
typedef __attribute__((ext_vector_type(4))) float f32x4;

__device__ inline unsigned short f2b(float f) {
    unsigned int u = __float_as_uint(f);
    unsigned int r = (u + 0x7fffu + ((u >> 16) & 1u)) >> 16;  // RNE
    return (unsigned short)r;
}
__device__ inline float b2f(unsigned short u) {
    return __uint_as_float(((unsigned int)u) << 16);
}

__device__ inline void gload16(const void* g, void* l) {
    typedef unsigned int __attribute__((address_space(1))) gu32;
    typedef unsigned int __attribute__((address_space(3))) su32;
    __builtin_amdgcn_global_load_lds((const gu32*)g, (su32*)l, 16, 0, 0);
}

// ---------------- CSR build ----------------

__global__ void k_zero_int(int* p, int n) {
    int i = blockIdx.x * blockDim.x + threadIdx.x;
    if (i < n) p[i] = 0;
}

__global__ void k_count(const int* __restrict__ dst, int* __restrict__ cnt, int E) {
    int i = blockIdx.x * blockDim.x + threadIdx.x;
    if (i < E) atomicAdd(&cnt[dst[i]], 1);
}

__global__ void k_dinv(const int* __restrict__ cnt, float* __restrict__ dinv, int n) {
    int i = blockIdx.x * blockDim.x + threadIdx.x;
    if (i < n) dinv[i] = rsqrtf((float)cnt[i] + 1.0f);
}

__global__ void k_scan1(const int* __restrict__ cnt, int* __restrict__ excl,
                        int* __restrict__ bsum, int n) {
    __shared__ int sh[SCAN_B];
    int t = threadIdx.x;
    int i = blockIdx.x * SCAN_B + t;
    int v = (i < n) ? cnt[i] : 0;
    sh[t] = v;
    __syncthreads();
    for (int off = 1; off < SCAN_B; off <<= 1) {
        int x = (t >= off) ? sh[t - off] : 0;
        __syncthreads();
        sh[t] += x;
        __syncthreads();
    }
    if (i < n) excl[i] = sh[t] - v;
    if (t == SCAN_B - 1) bsum[blockIdx.x] = sh[t];
}

__global__ void k_scan2(int* __restrict__ bsum, int nb) {
    __shared__ int sh[SCAN_B];
    int t = threadIdx.x;
    int v = (t < nb) ? bsum[t] : 0;
    sh[t] = v;
    __syncthreads();
    for (int off = 1; off < SCAN_B; off <<= 1) {
        int x = (t >= off) ? sh[t - off] : 0;
        __syncthreads();
        sh[t] += x;
        __syncthreads();
    }
    if (t < nb) bsum[t] = sh[t] - v;
}

__global__ void k_scan3(int* __restrict__ rowstart, const int* __restrict__ bsum,
                        int* __restrict__ cursor, int n, int E) {
    int i = blockIdx.x * SCAN_B + threadIdx.x;
    if (i < n) {
        rowstart[i] += bsum[blockIdx.x];
        cursor[i] = 0;
    }
    if (i == 0) rowstart[n] = E;
}

__global__ void k_scatter_csr(const int* __restrict__ src, const int* __restrict__ dst,
                              const float* __restrict__ dinv, const int* __restrict__ rowstart,
                              int* __restrict__ cursor, int2* __restrict__ csr, int E) {
    int e = blockIdx.x * blockDim.x + threadIdx.x;
    if (e >= E) return;
    int s = src[e], d = dst[e];
    int pos = rowstart[d] + atomicAdd(&cursor[d], 1);
    int2 c;
    c.x = s;
    c.y = __float_as_int(dinv[s] * dinv[d]);
    csr[pos] = c;
}

// ---------------- weight transpose + bf16 cast: WT[n][k] = bf16(W[k][n]) ----------------

__global__ void k_wt(const float* __restrict__ W, unsigned short* __restrict__ WT,
                     int K, int N) {
    int idx = blockIdx.x * 256 + threadIdx.x;
    if (idx >= K * N) return;
    int k = idx / N, n2 = idx - k * N;
    WT[(size_t)n2 * K + k] = f2b(W[idx]);
}

// ---------------- x -> bf16 (padded rows zeroed) ----------------

__global__ void k_x2b(const float* __restrict__ x, unsigned short* __restrict__ xb,
                      int n, int mpad) {
    int idx = blockIdx.x * 256 + threadIdx.x;   // one float4 / thread
    if (idx >= mpad * 32) return;               // 128/4 quads per row
    int row = idx >> 5;
    float4 v = {0.f, 0.f, 0.f, 0.f};
    if (row < n) v = ((const float4*)x)[idx];
    ushort4 o;
    o.x = f2b(v.x); o.y = f2b(v.y); o.z = f2b(v.z); o.w = f2b(v.w);
    ((ushort4*)xb)[idx] = o;
}

// ---------------- aggregation (bf16 rows, fp32 accumulate, bf16 out) ----------------

__device__ inline void acc8(float* a, uint4 u, float w) {
    a[0] += b2f(u.x & 0xffffu) * w; a[1] += b2f(u.x >> 16) * w;
    a[2] += b2f(u.y & 0xffffu) * w; a[3] += b2f(u.y >> 16) * w;
    a[4] += b2f(u.z & 0xffffu) * w; a[5] += b2f(u.z >> 16) * w;
    a[6] += b2f(u.w & 0xffffu) * w; a[7] += b2f(u.w >> 16) * w;
}

template <int F>
__global__ void k_aggb(const unsigned short* __restrict__ m, unsigned short* __restrict__ agg,
                       const int* __restrict__ rowstart, const int2* __restrict__ csr,
                       const float* __restrict__ dinv, int n, int mpad) {
    constexpr int TPN = F / 8;        // threads per node, 16B (8 bf16) each
    constexpr int NPB = 256 / TPN;
    int node = blockIdx.x * NPB + (int)(threadIdx.x / TPN);
    int fo = (int)(threadIdx.x % TPN) * 8;
    if (node >= mpad) return;
    uint4* dst = (uint4*)(agg + (size_t)node * F + fo);
    if (node >= n) { uint4 z = {0u, 0u, 0u, 0u}; *dst = z; return; }

    const unsigned short* mf = m + fo;
    float di = dinv[node];
    float a[8] = {};
    acc8(a, *(const uint4*)(mf + (size_t)node * F), di * di);  // self loop

    int b = rowstart[node], e = rowstart[node + 1];
    int j = b;
    for (; j + 4 <= e; j += 4) {
        int2 c0 = csr[j], c1 = csr[j + 1], c2 = csr[j + 2], c3 = csr[j + 3];
        uint4 u0 = *(const uint4*)(mf + (size_t)c0.x * F);
        uint4 u1 = *(const uint4*)(mf + (size_t)c1.x * F);
        uint4 u2 = *(const uint4*)(mf + (size_t)c2.x * F);
        uint4 u3 = *(const uint4*)(mf + (size_t)c3.x * F);
        acc8(a, u0, __int_as_float(c0.y));
        acc8(a, u1, __int_as_float(c1.y));
        acc8(a, u2, __int_as_float(c2.y));
        acc8(a, u3, __int_as_float(c3.y));
    }
    for (; j < e; ++j) {
        int2 c = csr[j];
        uint4 u = *(const uint4*)(mf + (size_t)c.x * F);
        acc8(a, u, __int_as_float(c.y));
    }
    uint4 o;
    o.x = (unsigned)f2b(a[0]) | ((unsigned)f2b(a[1]) << 16);
    o.y = (unsigned)f2b(a[2]) | ((unsigned)f2b(a[3]) << 16);
    o.z = (unsigned)f2b(a[4]) | ((unsigned)f2b(a[5]) << 16);
    o.w = (unsigned)f2b(a[6]) | ((unsigned)f2b(a[7]) << 16);
    *dst = o;
}

// ---------------- fused GEMM + bias + LayerNorm (+LeakyReLU), bf16 out ----------------
// C_row = LN(A[row,:] @ BT^T + bias); BM=64, BN = full output width, 4 waves,
// wave tile 64 x BN/4. XOR-swizzled LDS staging via global_load_lds (rule #21).

template <int BN, bool LRELU>
__global__ __launch_bounds__(256) void k_gemm_ln(
    const unsigned short* __restrict__ A, const unsigned short* __restrict__ BT,
    const float* __restrict__ bias, const float* __restrict__ g,
    const float* __restrict__ be, unsigned short* __restrict__ H, int K) {
    constexpr int WC = BN / 4;    // wave cols: 128 (BN=512) / 64 (BN=256)
    constexpr int NT = WC / 16;   // col fragments per wave: 8 / 4
    constexpr int BCH = BN / 32;  // B staging chunks per thread: 16 / 8

    __shared__ __align__(16) char sA[64 * BK * 2];   // 8 KB
    __shared__ __align__(16) char sB[BN * BK * 2];   // 64 / 32 KB
    __shared__ float sred[2][64][4];

    const int tid = threadIdx.x;
    const int lane = tid & 63;
    const int wc = tid >> 6;                          // wave id = col group
    const size_t row0 = (size_t)blockIdx.x * 64;

    // staging bases: chunk idx = c*256+tid; row = idx>>3 (+32 per c), col-chunk = idx&7
    const int arow = tid >> 3;
    const int acol = ((tid & 7) << 4) ^ ((arow & 7) << 4);  // inverse-swizzled byte col
    const unsigned short* srcA0 = A + (row0 + arow) * K + (acol >> 1);
    const unsigned short* srcB0 = BT + (size_t)arow * K + (acol >> 1);
    char* dstA0 = sA + tid * 16;
    char* dstB0 = sB + tid * 16;
    const size_t srcStep = (size_t)32 * K;   // elements per chunk-group

    // fragment read offsets (swizzled)
    const int fr = lane & 15;
    const int fg = lane >> 4;
    const int fsw = (lane & 7) << 4;
    int offA[4][2], offB[NT][2];
#pragma unroll
    for (int t = 0; t < 4; ++t)
#pragma unroll
        for (int kk = 0; kk < 2; ++kk)
            offA[t][kk] = (t * 16 + fr) * 128 + ((kk * 64 + fg * 16) ^ fsw);
#pragma unroll
    for (int t = 0; t < NT; ++t)
#pragma unroll
        for (int kk = 0; kk < 2; ++kk)
            offB[t][kk] = (wc * WC + t * 16 + fr) * 128 + ((kk * 64 + fg * 16) ^ fsw);

    f32x4 acc[4][NT] = {};

    for (int k0 = 0; k0 < K; k0 += BK) {
#pragma unroll
        for (int c = 0; c < 2; ++c) gload16(srcA0 + k0 + c * srcStep, dstA0 + c * 4096);
#pragma unroll
        for (int c = 0; c < BCH; ++c) gload16(srcB0 + k0 + c * srcStep, dstB0 + c * 4096);
        __syncthreads();
#pragma unroll
        for (int kk = 0; kk < 2; ++kk) {
            bfrag8 av[4], bv[NT];
#pragma unroll
            for (int t = 0; t < 4; ++t) av[t] = *(const bfrag8*)(sA + offA[t][kk]);
#pragma unroll
            for (int t = 0; t < NT; ++t) bv[t] = *(const bfrag8*)(sB + offB[t][kk]);
#pragma unroll
            for (int i = 0; i < 4; ++i)
#pragma unroll
                for (int j = 0; j < NT; ++j)
                    acc[i][j] = __builtin_amdgcn_mfma_f32_16x16x32_bf16(av[i], bv[j],
                                                                        acc[i][j], 0, 0, 0);
        }
        __syncthreads();
    }

    // ---- epilogue: bias, row stats, LN, (LeakyReLU), bf16 store ----
    float bb[NT], gg[NT], ee[NT];
#pragma unroll
    for (int j = 0; j < NT; ++j) {
        int col = wc * WC + j * 16 + fr;
        bb[j] = bias[col]; gg[j] = g[col]; ee[j] = be[col];
    }

    float s[4][4], sq[4][4];   // [i][q] partial over this lane's NT cols
#pragma unroll
    for (int i = 0; i < 4; ++i)
#pragma unroll
        for (int q = 0; q < 4; ++q) {
            float ss = 0.f, qq = 0.f;
#pragma unroll
            for (int j = 0; j < NT; ++j) {
                float v = acc[i][j][q] + bb[j];
                acc[i][j][q] = v;
                ss += v; qq += v * v;
            }
            s[i][q] = ss; sq[i][q] = qq;
        }
    // reduce across the 16 fr-lanes (same rows, different cols)
#pragma unroll
    for (int m = 1; m < 16; m <<= 1)
#pragma unroll
        for (int i = 0; i < 4; ++i)
#pragma unroll
            for (int q = 0; q < 4; ++q) {
                s[i][q] += __shfl_xor(s[i][q], m);
                sq[i][q] += __shfl_xor(sq[i][q], m);
            }
    if (fr == 0) {
#pragma unroll
        for (int i = 0; i < 4; ++i)
#pragma unroll
            for (int q = 0; q < 4; ++q) {
                int r = i * 16 + fg * 4 + q;
                sred[0][r][wc] = s[i][q];
                sred[1][r][wc] = sq[i][q];
            }
    }
    __syncthreads();

#pragma unroll
    for (int i = 0; i < 4; ++i)
#pragma unroll
        for (int q = 0; q < 4; ++q) {
            int r = i * 16 + fg * 4 + q;
            float S = sred[0][r][0] + sred[0][r][1] + sred[0][r][2] + sred[0][r][3];
            float Q = sred[1][r][0] + sred[1][r][1] + sred[1][r][2] + sred[1][r][3];
            float mu = S * (1.0f / BN);
            float var = Q * (1.0f / BN) - mu * mu;
            float rs = rsqrtf(var + 1e-5f);
            size_t grow = (row0 + r) * BN;
#pragma unroll
            for (int j = 0; j < NT; ++j) {
                float y = (acc[i][j][q] - mu) * rs * gg[j] + ee[j];
                if (LRELU) y = (y > 0.f) ? y : 0.01f * y;
                H[grow + wc * WC + j * 16 + fr] = f2b(y);
            }
        }
}

// ---------------- pooling: chunked partial sums + atomics ----------------

__global__ void k_pzero(float* p) { p[blockIdx.x * 256 + threadIdx.x] = 0.f; }

__global__ void k_pool2(const unsigned short* __restrict__ h, const int* __restrict__ batch,
                        float* __restrict__ pooled, int n) {
    int i0 = blockIdx.x * PCH;
    int iend = i0 + PCH; if (iend > n) iend = n;
    int t = threadIdx.x;  // 256 threads x 2 features
    float s0 = 0.f, s1 = 0.f;
    int cur = batch[i0];
    for (int i = i0; i < iend; ++i) {
        int g = batch[i];
        if (g != cur) {  // block-uniform branch
            atomicAdd(&pooled[(size_t)cur * 512 + t * 2], s0);
            atomicAdd(&pooled[(size_t)cur * 512 + t * 2 + 1], s1);
            s0 = s1 = 0.f;
            cur = g;
        }
        unsigned int u = *(const unsigned int*)(h + (size_t)i * 512 + t * 2);
        s0 += b2f(u & 0xffffu);
        s1 += b2f(u >> 16);
    }
    atomicAdd(&pooled[(size_t)cur * 512 + t * 2], s0);
    atomicAdd(&pooled[(size_t)cur * 512 + t * 2 + 1], s1);
}

// ---------------- final linear: out[G,128] = (pooled/cnt) @ Wf + bf ----------------

__global__ void k_final(const float* __restrict__ pooled, const int* __restrict__ batch,
                        const float* __restrict__ Wf, const float* __restrict__ bf,
                        float* __restrict__ out, int n) {
    int gph = blockIdx.x;
    int o = threadIdx.x;  // 128
    int lo = 0, hi = n;
    while (lo < hi) { int mid = (lo + hi) >> 1; if (batch[mid] < gph) lo = mid + 1; else hi = mid; }
    int start = lo;
    lo = start; hi = n;
    while (lo < hi) { int mid = (lo + hi) >> 1; if (batch[mid] < gph + 1) lo = mid + 1; else hi = mid; }
    int end = lo;
    float inv = 1.0f / fmaxf((float)(end - start), 1.0f);

    __shared__ float p[512];
    for (int k = threadIdx.x; k < 512; k += 128) p[k] = pooled[(size_t)gph * 512 + k] * inv;
    __syncthreads();
    float acc = bf[o];
#pragma unroll 8
    for (int k = 0; k < 512; ++k) acc += p[k] * Wf[(size_t)k * 128 + o];
    out[(size_t)gph * 128 + o] = acc;
}

// ---------------- host ----------------

static inline size_t align_up(size_t x) { return (x + 255) & ~(size_t)255; }

extern "C" void kernel_launch(void* const* d_in, const int* in_sizes, int n_in,
                              void* d_out, int out_size, void* d_ws, size_t ws_size,
                              hipStream_t stream) {
    const float* x     = (const float*)d_in[0];
    const int*   ei    = (const int*)d_in[1];
    const int*   batch = (const int*)d_in[2];
    const float* W1 = (const float*)d_in[4],  *b1 = (const float*)d_in[5];
    const float* g1 = (const float*)d_in[6],  *be1= (const float*)d_in[7];
    const float* W2 = (const float*)d_in[8],  *b2 = (const float*)d_in[9];
    const float* g2 = (const float*)d_in[10], *be2= (const float*)d_in[11];
    const float* W3 = (const float*)d_in[12], *b3 = (const float*)d_in[13];
    const float* g3 = (const float*)d_in[14], *be3= (const float*)d_in[15];
    const float* Wf = (const float*)d_in[16], *bf = (const float*)d_in[17];
    float* out = (float*)d_out;

    const int N = in_sizes[0] / 128;   // 50000
    const int E = in_sizes[1] / 2;     // 800000
    const int Mpad = ((N + 63) / 64) * 64;   // 50048 (also /128 for agg grids)
    const int* src = ei;
    const int* dst = ei + E;

    char* ws = (char*)d_ws;
    size_t off = 0;
    auto take = [&](size_t bytes) { char* p = ws + off; off += align_up(bytes); return p; };

    unsigned short* aggb    = (unsigned short*)take((size_t)Mpad * 512 * 2);
    unsigned short* hb      = (unsigned short*)take((size_t)Mpad * 512 * 2);
    unsigned short* xb      = (unsigned short*)take((size_t)Mpad * 128 * 2);
    unsigned short* wt1     = (unsigned short*)take((size_t)256 * 128 * 2);
    unsigned short* wt2     = (unsigned short*)take((size_t)512 * 256 * 2);
    unsigned short* wt3     = (unsigned short*)take((size_t)512 * 512 * 2);
    float*          dinv    = (float*)take((size_t)N * 4);
    int*            rowstart= (int*)  take((size_t)(N + 1) * 4);
    int*            cnt     = (int*)  take((size_t)N * 4);
    int*            cursor  = (int*)  take((size_t)N * 4);
    int*            bsum    = (int*)  take((size_t)SCAN_B * 4);
    int2*           csr     = (int2*) take((size_t)E * 8);
    float*          pooled  = (float*)take((size_t)GRAPHS * 512 * 4);

    const int nb = (N + SCAN_B - 1) / SCAN_B;

    // CSR build
    k_zero_int<<<(N + 255) / 256, 256, 0, stream>>>(cnt, N);
    k_count<<<(E + 255) / 256, 256, 0, stream>>>(dst, cnt, E);
    k_dinv<<<(N + 255) / 256, 256, 0, stream>>>(cnt, dinv, N);
    k_scan1<<<nb, SCAN_B, 0, stream>>>(cnt, rowstart, bsum, N);
    k_scan2<<<1, SCAN_B, 0, stream>>>(bsum, nb);
    k_scan3<<<nb, SCAN_B, 0, stream>>>(rowstart, bsum, cursor, N, E);
    k_scatter_csr<<<(E + 255) / 256, 256, 0, stream>>>(src, dst, dinv, rowstart, cursor, csr, E);

    // weights -> bf16 transposed
    k_wt<<<(128 * 256 + 255) / 256, 256, 0, stream>>>(W1, wt1, 128, 256);
    k_wt<<<(256 * 512 + 255) / 256, 256, 0, stream>>>(W2, wt2, 256, 512);
    k_wt<<<(512 * 512 + 255) / 256, 256, 0, stream>>>(W3, wt3, 512, 512);

    // x -> bf16 (padded)
    k_x2b<<<(Mpad * 32 + 255) / 256, 256, 0, stream>>>(x, xb, N, Mpad);

    // Layer 1: agg(x) -> GEMM(K=128,N=256)+LN+lrelu -> hb[.,256]
    k_aggb<128><<<Mpad / 16, 256, 0, stream>>>(xb, aggb, rowstart, csr, dinv, N, Mpad);
    k_gemm_ln<256, true><<<Mpad / 64, 256, 0, stream>>>(aggb, wt1, b1, g1, be1, hb, 128);

    // Layer 2: agg(hb[.,256]) -> GEMM(K=256,N=512)+LN+lrelu -> hb[.,512]
    k_aggb<256><<<Mpad / 8, 256, 0, stream>>>(hb, aggb, rowstart, csr, dinv, N, Mpad);
    k_gemm_ln<512, true><<<Mpad / 64, 256, 0, stream>>>(aggb, wt2, b2, g2, be2, hb, 256);

    // Layer 3: agg(hb[.,512]) -> GEMM(K=512,N=512)+LN -> hb[.,512]
    k_aggb<512><<<Mpad / 4, 256, 0, stream>>>(hb, aggb, rowstart, csr, dinv, N, Mpad);
    k_gemm_ln<512, false><<<Mpad / 64, 256, 0, stream>>>(aggb, wt3, b3, g3, be3, hb, 512);

    // pool + final
    k_pzero<<<GRAPHS * 512 / 256, 256, 0, stream>>>(pooled);
    k_pool2<<<(N + PCH - 1) / PCH, 256, 0, stream>>>(hb, batch, pooled, N);
    k_final<<<GRAPHS, 128, 0, stream>>>(pooled, batch, Wf, bf, out, N);
}